// Round 14
// baseline (232.543 us; speedup 1.0000x reference)
//
#include <hip/hip_runtime.h>
#include <stdint.h>

#define BB 256
#define TT 2048
#define KK 64
#define CHUNK 64
#define NCHUNK (TT / CHUNK)   // 32
#define WARM 32
#define NSEG 16
#define SEGLEN (TT / NSEG)    // 128

__device__ __forceinline__ unsigned umax3(unsigned a, unsigned b, unsigned c) {
    return max(max(a, b), c);   // v_max3_u32
}

// ============================ kernel 1: forward ============================
// grid 4096 x 64 threads: block = one wave = (batch b = idx>>4, segment s = idx&15).
// Lane l owns tag-row l. fv kept per-lane as fixed-point (value*2048)<<6 with the
// low 6 bits zero; broadcast via v_readlane (SGPR). Transition row pre-baked as
// trk[p] = (round(clamp(tr,-256)*2048) << 6) | (63-p), so one v_add_u32 produces
// the packed (value,index) comparison key: u32 max = max AND first-argmax.
// No LDS, no barriers: the recurrence is wave-private.
__global__ __launch_bounds__(64, 4)
void viterbi_fwd_reg(const float* __restrict__ feats,
                     const float* __restrict__ trans,
                     const int* __restrict__ start_tag_p,
                     const int* __restrict__ stop_tag_p,
                     float* __restrict__ out,
                     unsigned char* __restrict__ bp_ws)
{
    const int bid  = blockIdx.x;
    const int b    = bid >> 4;
    const int s    = bid & 15;
    const int t0   = s * SEGLEN - (s ? WARM : 0);
    const int warmN = s ? WARM : 0;
    const int L    = warmN + SEGLEN;          // 128 or 160
    const int lane = threadIdx.x;             // 64-thread block = 1 wave

    const int start_tag = *start_tag_p;
    const int stop_tag  = *stop_tag_p;

    const float* fb = feats + (size_t)b * TT * KK + (size_t)t0 * KK + lane;
    unsigned char* bpb = bp_ws + (size_t)b * TT * KK;

    // pre-bake transition row (one-time; trans is 16KB, L1/L2-hot)
    int trk[64];
#pragma unroll
    for (int p = 0; p < 64; ++p) {
        const float tv = fmaxf(trans[lane * KK + p], -256.0f);   // soft -inf
        trk[p] = (((int)rintf(tv * 2048.0f)) << 6) | (63 - p);
    }

    // fv init (positive domain, fixed<<6): start=2048, others=512; warm segs all 2048
    int fv = ((s || lane == start_tag) ? (2048 * 2048) : (512 * 2048)) << 6;

    // feat prefetch ring (depth 4)
    float r0 = fb[0 * KK], r1 = fb[1 * KK], r2 = fb[2 * KK], r3 = fb[3 * KK];

    auto stepf = [&](float featval, bool st, int tau) {
        const int fvb = fv;
        unsigned acc[8];
#pragma unroll
        for (int q = 0; q < 8; ++q) acc[q] = 0u;
#pragma unroll
        for (int p = 0; p < 64; ++p) {
            const int sp = __builtin_amdgcn_readlane(fvb, p);    // SGPR broadcast
            const unsigned c = (unsigned)(sp + trk[p]);          // packed key, free
            acc[p & 7] = max(acc[p & 7], c);
        }
        const unsigned K = umax3(umax3(acc[0], acc[1], acc[2]),
                                 umax3(acc[3], acc[4], acc[5]),
                                 max(acc[6], acc[7]));
        if (st)
            bpb[(size_t)(t0 + tau) * KK + lane] = (unsigned char)(63 - (K & 63u));
        const int fsh = ((int)rintf(featval * 2048.0f)) << 6;
        fv = (int)(K & 0xFFFFFFC0u) + fsh;                       // low 6 bits stay 0
    };

    // warm steps (no bp stores); warmN is 0 or 32, multiple of 4
    for (int tau = 0; tau < warmN; tau += 4) {
        float n0 = fb[(tau + 4) * KK]; stepf(r0, false, tau + 0); r0 = n0;
        float n1 = fb[(tau + 5) * KK]; stepf(r1, false, tau + 1); r1 = n1;
        float n2 = fb[(tau + 6) * KK]; stepf(r2, false, tau + 2); r2 = n2;
        float n3 = fb[(tau + 7) * KK]; stepf(r3, false, tau + 3); r3 = n3;
    }
    // owned steps (bp stores)
    for (int tau = warmN; tau < L; tau += 4) {
        float n0 = fb[min(tau + 4, L - 1) * KK]; stepf(r0, true, tau + 0); r0 = n0;
        float n1 = fb[min(tau + 5, L - 1) * KK]; stepf(r1, true, tau + 1); r1 = n1;
        float n2 = fb[min(tau + 6, L - 1) * KK]; stepf(r2, true, tau + 2); r2 = n2;
        float n3 = fb[min(tau + 7, L - 1) * KK]; stepf(r3, true, tau + 3); r3 = n3;
    }

    // terminal argmax (last segment): uniform warm offset cancels in argmax;
    // true score recomputed from the decoded path in kernel 2.
    if (s == NSEG - 1) {
        const float fvf = (float)(fv >> 6) * (1.0f / 2048.0f);
        float bv = fvf + trans[stop_tag * KK + lane];
        int bi = lane;
#pragma unroll
        for (int off = 1; off < 64; off <<= 1) {
            const float ov = __shfl_xor(bv, off);
            const int   oi = __shfl_xor(bi, off);
            const bool take = (ov > bv) || (ov == bv && oi < bi);
            bv = take ? ov : bv;
            bi = take ? oi : bi;
        }
        if (lane == 0) out[b] = (float)bi;   // carrier for bestlast -> k2
    }
}

// ====================== kernel 2: backtrace + score ======================
__global__ __launch_bounds__(512)
void viterbi_bt_score(const float* __restrict__ feats,
                      const float* __restrict__ trans,
                      const int* __restrict__ start_tag_p,
                      const int* __restrict__ stop_tag_p,
                      float* __restrict__ out,
                      const unsigned char* __restrict__ bp_ws)
{
    const int b    = blockIdx.x;
    const int tid  = threadIdx.x;
    const int lane = tid & 63;
    const int w    = __builtin_amdgcn_readfirstlane(tid >> 6);  // 0..7

    __shared__ int cmap[NCHUNK][KK];
    __shared__ int be_lds[NCHUNK];
    __shared__ unsigned char path_lds[TT];
    __shared__ float red_lds[8];

    const unsigned char* bpb = bp_ws + (size_t)b * TT * KK;

    // ---- chunk-map composition: wave w composes chunks 4w..4w+3 ----
    {
        const int c0 = w * 4;
        const unsigned char* q0 = bpb + (size_t)(c0 + 0) * CHUNK * KK + lane;
        const unsigned char* q1 = bpb + (size_t)(c0 + 1) * CHUNK * KK + lane;
        const unsigned char* q2 = bpb + (size_t)(c0 + 2) * CHUNK * KK + lane;
        const unsigned char* q3 = bpb + (size_t)(c0 + 3) * CHUNK * KK + lane;
        int M0 = lane, M1 = lane, M2 = lane, M3 = lane;
        int a0 = q0[0], a1 = q1[0], a2 = q2[0], a3 = q3[0];
        int b0 = q0[KK], b1 = q1[KK], b2 = q2[KK], b3 = q3[KK];
        for (int t = 0; t < CHUNK; t += 2) {
            int n0 = 0, n1 = 0, n2 = 0, n3 = 0, m0 = 0, m1 = 0, m2 = 0, m3 = 0;
            if (t + 2 < CHUNK) {
                n0 = q0[(t + 2) * KK]; n1 = q1[(t + 2) * KK];
                n2 = q2[(t + 2) * KK]; n3 = q3[(t + 2) * KK];
                m0 = q0[(t + 3) * KK]; m1 = q1[(t + 3) * KK];
                m2 = q2[(t + 3) * KK]; m3 = q3[(t + 3) * KK];
            }
            M0 = __shfl(M0, a0); M1 = __shfl(M1, a1);
            M2 = __shfl(M2, a2); M3 = __shfl(M3, a3);
            M0 = __shfl(M0, b0); M1 = __shfl(M1, b1);
            M2 = __shfl(M2, b2); M3 = __shfl(M3, b3);
            a0 = n0; a1 = n1; a2 = n2; a3 = n3;
            b0 = m0; b1 = m1; b2 = m2; b3 = m3;
        }
        cmap[c0 + 0][lane] = M0; cmap[c0 + 1][lane] = M1;
        cmap[c0 + 2][lane] = M2; cmap[c0 + 3][lane] = M3;
    }
    __syncthreads();

    // ---- chunk-boundary tags (serial, 32 LDS hops) ----
    if (tid == 0) {
        int x = (int)out[b];          // bestlast from k1
        be_lds[NCHUNK - 1] = x;
        for (int c = NCHUNK - 1; c >= 1; --c) {
            x = cmap[c][x];
            be_lds[c - 1] = x;
        }
    }
    __syncthreads();

    // ---- parallel interior backtrace (32 chunks), also fill path_lds ----
    if (tid < NCHUNK) {
        const int c = tid;
        int x = be_lds[c];
        float* po = out + BB + (size_t)b * TT;
        for (int t = (c + 1) * CHUNK - 1; t >= c * CHUNK; --t) {
            po[t] = (float)x;
            path_lds[t] = (unsigned char)x;
            x = (int)bpb[(size_t)t * KK + x];
        }
    }
    __syncthreads();

    // ---- exact score recompute along the decoded path ----
    const float* fbb = feats + (size_t)b * TT * KK;
    const int start_tag = *start_tag_p;
    const int stop_tag  = *stop_tag_p;
    float acc = 0.0f;
    for (int t = tid; t < TT; t += 512) {
        const int xt = path_lds[t];
        const int xp = (t > 0) ? (int)path_lds[t - 1] : start_tag;
        acc += fbb[(size_t)t * KK + xt] + trans[xt * KK + xp];
    }
    if (tid == 0) acc += trans[stop_tag * KK + (int)path_lds[TT - 1]];
#pragma unroll
    for (int off = 1; off < 64; off <<= 1) acc += __shfl_xor(acc, off);
    if (lane == 0) red_lds[w] = acc;
    __syncthreads();
    if (tid == 0) {
        float sc = 0.0f;
        for (int i = 0; i < 8; ++i) sc += red_lds[i];
        out[b] = sc;
    }
}

extern "C" void kernel_launch(void* const* d_in, const int* in_sizes, int n_in,
                              void* d_out, int out_size, void* d_ws, size_t ws_size,
                              hipStream_t stream) {
    const float* feats = (const float*)d_in[0];
    const float* trans = (const float*)d_in[1];
    const int* start_tag = (const int*)d_in[2];
    const int* stop_tag  = (const int*)d_in[3];
    float* out = (float*)d_out;
    unsigned char* bp = (unsigned char*)d_ws;   // B*T*K = 33.5 MB backpointers

    viterbi_fwd_reg<<<BB * NSEG, 64, 0, stream>>>(feats, trans, start_tag, stop_tag, out, bp);
    viterbi_bt_score<<<BB, 512, 0, stream>>>(feats, trans, start_tag, stop_tag, out, bp);
}